// Round 1
// baseline (197.598 us; speedup 1.0000x reference)
//
#include <hip/hip_runtime.h>
#include <stdint.h>

// Problem shapes (fixed): B=32, N=900, C=91. ALL float32 in and out.
// d_in[0]: bboxes f32 [32,900,4] (cxcywh)   d_in[1]: logits f32 [32,900,91]
// d_out f32 concat: agg [32,900,4] | logits [32,900,91] | adj [32,900,900]
#define NQ 900
#define NB 32
#define WORDS 16            // u64 bitmask words per row (15 used, 1 pad)
#define ROWS_PER_BLK 30     // k_mask rows per block (30 blocks per batch)

// element (f32) offsets inside d_out
#define AGG_ELE   0                    // 115200 elems
#define LOG_ELE   115200               // 2620800 elems
#define ADJ_ELE   2736000              // 25920000 elems
// scratch aliases inside d_out (overwritten later in stream order):
//   bit rows (3.69 MB) -> start of adj region (103.7 MB)
//   labels  (115 KB)   -> start of logits region (10.5 MB)

// ---------------------------------------------------------------------------
// Kernel 1: pairwise GIoU > 0.9 bitmask, upper triangle (j >= i) per row.
// Exact reference op order in f32, contraction off => the 0.9 compare is
// bit-identical to the np f32 reference. Mask is exactly symmetric (all ops
// commutative in f32), so upper triangle suffices.
// ---------------------------------------------------------------------------
__global__ __launch_bounds__(256) void k_mask(const float4* __restrict__ bb,
                                              unsigned long long* __restrict__ bits)
{
#pragma clang fp contract(off)
    __shared__ float sx1[NQ], sy1[NQ], sx2[NQ], sy2[NQ], sar[NQ];
    const int blk   = blockIdx.x;
    const int b     = blk / (NQ / ROWS_PER_BLK);
    const int chunk = blk % (NQ / ROWS_PER_BLK);
    const int row0  = chunk * ROWS_PER_BLK;
    const int tid   = threadIdx.x;

    for (int i = tid; i < NQ; i += 256) {
        float4 q = bb[b * NQ + i];
        float cx = q.x, cy = q.y, w = q.z, h = q.w;
        float hw = 0.5f * w, hh = 0.5f * h;       // exact (pow2 scale)
        float x1 = cx - hw, y1 = cy - hh, x2 = cx + hw, y2 = cy + hh;
        sx1[i] = x1; sy1[i] = y1; sx2[i] = x2; sy2[i] = y2;
        sar[i] = (x2 - x1) * (y2 - y1);           // ref: area from xyxy
    }
    __syncthreads();

    const int wave = tid >> 6, lane = tid & 63;
    for (int r = row0; r < row0 + ROWS_PER_BLK; ++r) {
        float x1i = sx1[r], y1i = sy1[r], x2i = sx2[r], y2i = sy2[r], ai = sar[r];
        unsigned long long* rowp = bits + (size_t)(b * NQ + r) * WORDS;
        for (int t = 0; t < 4; ++t) {
            int word  = wave + 4 * t;      // 0..15
            int jbase = word << 6;
            if (jbase + 64 <= r) {         // whole word strictly below diagonal
                if (lane == 0) rowp[word] = 0ULL;
                continue;
            }
            int j = jbase + lane;
            bool pred = false;
            if (j >= r && j < NQ) {
                float x1j = sx1[j], y1j = sy1[j], x2j = sx2[j], y2j = sy2[j], aj = sar[j];
                float ltx = fmaxf(x1i, x1j), lty = fmaxf(y1i, y1j);
                float rbx = fminf(x2i, x2j), rby = fminf(y2i, y2j);
                float iw  = fmaxf(rbx - ltx, 0.0f), ih = fmaxf(rby - lty, 0.0f);
                float inter = iw * ih;
                float uni   = ai + aj - inter;
                float iou   = inter / uni;                 // 0/0 -> NaN (degenerate)
                float ex1 = fminf(x1i, x1j), ey1 = fminf(y1i, y1j);
                float ex2 = fmaxf(x2i, x2j), ey2 = fmaxf(y2i, y2j);
                float ew  = fmaxf(ex2 - ex1, 0.0f), eh2 = fmaxf(ey2 - ey1, 0.0f);
                float ae  = ew * eh2;
                float g   = iou - (ae - uni) / ae;
                pred = (g > 0.9f);                         // NaN -> false, matches np
            }
            unsigned long long m = __ballot(pred);
            if (lane == 0) rowp[word] = m;
        }
    }
}

// ---------------------------------------------------------------------------
// Kernel 2: connected components (min-label propagation, one block/batch),
// then component-mean aggregation -> f32 agg. Labels parked in the
// not-yet-written logits output region.
// ---------------------------------------------------------------------------
__global__ __launch_bounds__(1024) void k_label(const unsigned long long* __restrict__ bits,
                                                const float4* __restrict__ bb,
                                                int* __restrict__ labg,
                                                float4* __restrict__ agg_out)
{
    __shared__ int   lab[NQ];
    __shared__ float scx[NQ], scy[NQ], sw[NQ], sh[NQ], scnt[NQ];
    __shared__ int   changed;
    const int b   = blockIdx.x;
    const int tid = threadIdx.x;
    const size_t base = (size_t)b * NQ;

    for (int i = tid; i < NQ; i += 1024) {
        unsigned long long selfw = bits[(base + i) * WORDS + (i >> 6)];
        bool alive = (selfw >> (i & 63)) & 1ULL;   // degenerate box: self-GIoU NaN
        lab[i] = alive ? i : -1;
        scx[i] = 0.f; scy[i] = 0.f; sw[i] = 0.f; sh[i] = 0.f; scnt[i] = 0.f;
    }
    if (tid == 0) changed = 0;
    __syncthreads();

    for (int iter = 0; iter < 1024; ++iter) {
        for (int i = tid; i < NQ; i += 1024) {
            int li = lab[i];
            if (li < 0) continue;
            const unsigned long long* rowp = bits + (base + i) * WORDS;
            for (int k = i >> 6; k < 15; ++k) {
                unsigned long long w = rowp[k];
                while (w) {
                    int j = (k << 6) + __builtin_ctzll(w);
                    w &= w - 1;
                    int lj = lab[j];
                    if (lj < li)      { li = lj; changed = 1; }
                    else if (lj > li) { atomicMin(&lab[j], li); changed = 1; }
                }
            }
            if (li < lab[i]) atomicMin(&lab[i], li);
        }
        __syncthreads();
        for (int i = tid; i < NQ; i += 1024) {       // pointer-jump compress
            int li = lab[i];
            if (li > 0) {
                int l2 = lab[li];
                if (l2 < li) lab[i] = l2;            // benign race, monotone decrease
            }
        }
        __syncthreads();
        int done = (changed == 0);
        __syncthreads();
        if (done) break;
        if (tid == 0) changed = 0;
        __syncthreads();
    }

    for (int i = tid; i < NQ; i += 1024) {
        int li = lab[i];
        if (li >= 0) {
            float4 q = bb[base + i];
            atomicAdd(&scx[li], q.x);
            atomicAdd(&scy[li], q.y);
            atomicAdd(&sw [li], q.z);
            atomicAdd(&sh [li], q.w);
            atomicAdd(&scnt[li], 1.0f);
        }
    }
    __syncthreads();

    for (int i = tid; i < NQ; i += 1024) {
        int li = lab[i];
        labg[base + i] = li;
        float4 o;
        if (li >= 0) {
            float d = scnt[li] + 1e-6f;
            o.x = scx[li] / d; o.y = scy[li] / d;
            o.z = sw [li] / d; o.w = sh [li] / d;
        } else {
            o.x = 0.f; o.y = 0.f; o.z = 0.f; o.w = 0.f;   // ref: 0 / 1e-6 = 0
        }
        agg_out[base + i] = o;
    }
}

// ---------------------------------------------------------------------------
// Kernel 3: adj[b][i][j] = (lab[j]==lab[i] && alive) ? 1.0f : 0.0f
// One block per row; 16B/lane coalesced stores. Pure streaming write (104 MB).
// ---------------------------------------------------------------------------
__global__ __launch_bounds__(256) void k_adj(const int* __restrict__ labg,
                                             float4* __restrict__ adj)
{
    const int row = blockIdx.x;            // b*900 + i
    const int b = row / NQ;
    const int li = labg[row];
    const int4* lj4 = (const int4*)(labg + (size_t)b * NQ);
    float4* out = adj + (size_t)row * (NQ / 4);
    for (int t = threadIdx.x; t < NQ / 4; t += 256) {
        int4 l = lj4[t];
        float4 o;
        o.x = (l.x == li && li >= 0) ? 1.0f : 0.f;
        o.y = (l.y == li && li >= 0) ? 1.0f : 0.f;
        o.z = (l.z == li && li >= 0) ? 1.0f : 0.f;
        o.w = (l.w == li && li >= 0) ? 1.0f : 0.f;
        out[t] = o;
    }
}

// ---------------------------------------------------------------------------
// Kernel 4: logits passthrough as a COPY KERNEL, not hipMemcpyAsync.
// Under graph capture hipMemcpyAsync D2D records an SDMA memcpy node
// (~150 GB/s, invisible to kernel counters) — it was ~140 us of the 195 us
// total. A float4 blit kernel does the same 21 MB of traffic at HBM rate.
// Must run AFTER k_adj (labels scratch aliases the logits output region).
// ---------------------------------------------------------------------------
#define LOG_F4 655200      // 2620800 floats / 4
__global__ __launch_bounds__(256) void k_copy(const float4* __restrict__ src,
                                              float4* __restrict__ dst)
{
    int i = blockIdx.x * 256 + threadIdx.x;
    if (i < LOG_F4) dst[i] = src[i];
}

extern "C" void kernel_launch(void* const* d_in, const int* in_sizes, int n_in,
                              void* d_out, int out_size, void* d_ws, size_t ws_size,
                              hipStream_t stream) {
    (void)in_sizes; (void)n_in; (void)out_size; (void)d_ws; (void)ws_size;
    const float4* bb = (const float4*)d_in[0];
    const float4* logits = (const float4*)d_in[1];
    float* outf = (float*)d_out;

    unsigned long long* bits = (unsigned long long*)(outf + ADJ_ELE); // scratch
    int*    labg = (int*)(outf + LOG_ELE);                            // scratch
    float4* agg  = (float4*)(outf + AGG_ELE);
    float4* adj  = (float4*)(outf + ADJ_ELE);

    hipLaunchKernelGGL(k_mask,  dim3(NB * (NQ / ROWS_PER_BLK)), dim3(256), 0, stream, bb, bits);
    hipLaunchKernelGGL(k_label, dim3(NB), dim3(1024), 0, stream, bits, bb, labg, agg);
    hipLaunchKernelGGL(k_adj,   dim3(NB * NQ), dim3(256), 0, stream, labg, adj);
    // logits f32 passthrough last (overwrites label scratch; stream-ordered)
    hipLaunchKernelGGL(k_copy,  dim3((LOG_F4 + 255) / 256), dim3(256), 0, stream,
                       logits, (float4*)(outf + LOG_ELE));
}

// Round 2
// 189.519 us; speedup vs baseline: 1.0426x; 1.0426x over previous
//
#include <hip/hip_runtime.h>
#include <stdint.h>

// Problem shapes (fixed): B=32, N=900, C=91. ALL float32 in and out.
// d_in[0]: bboxes f32 [32,900,4] (cxcywh)   d_in[1]: logits f32 [32,900,91]
// d_out f32 concat: agg [32,900,4] | logits [32,900,91] | adj [32,900,900]
#define NQ 900
#define NB 32
#define WORDS 16            // u64 bitmask words per row (15 used, 1 pad)
#define ROWS_PER_BLK 30     // k_mask rows per block (30 blocks per batch)
#define MASK_BLKS (NB * (NQ / ROWS_PER_BLK))   // 960
#define LOG_F4 655200       // 2620800 floats / 4
#define COPY_BLKS ((LOG_F4 + 255) / 256)       // 2560

// element (f32) offsets inside d_out
#define AGG_ELE   0                    // 115200 elems
#define LOG_ELE   115200               // 2620800 elems
#define ADJ_ELE   2736000              // 25920000 elems

// workspace layout (preferred): bits [3.6864 MB] | labg [115.2 KB]
#define WS_BITS_BYTES  (sizeof(unsigned long long) * NB * NQ * WORDS)  // 3686400
#define WS_LABG_BYTES  (sizeof(int) * NB * NQ)                         // 115200
#define WS_NEEDED      (WS_BITS_BYTES + WS_LABG_BYTES)

// ---------------------------------------------------------------------------
// Kernel 1: blocks [0,960): pairwise GIoU > 0.9 bitmask, upper triangle
// (j >= i) per row — exact reference f32 op order, contraction off.
// blocks [960, 960+2560): logits passthrough copy (independent work folded
// into the same launch so it overlaps the compute-light mask blocks).
// ---------------------------------------------------------------------------
__global__ __launch_bounds__(256) void k_mask(const float4* __restrict__ bb,
                                              unsigned long long* __restrict__ bits,
                                              const float4* __restrict__ logits,
                                              float4* __restrict__ logits_out)
{
#pragma clang fp contract(off)
    const int blk = blockIdx.x;
    if (blk >= MASK_BLKS) {                 // copy role
        int i = (blk - MASK_BLKS) * 256 + threadIdx.x;
        if (i < LOG_F4) logits_out[i] = logits[i];
        return;
    }

    __shared__ float sx1[NQ], sy1[NQ], sx2[NQ], sy2[NQ], sar[NQ];
    const int b     = blk / (NQ / ROWS_PER_BLK);
    const int chunk = blk % (NQ / ROWS_PER_BLK);
    const int row0  = chunk * ROWS_PER_BLK;
    const int tid   = threadIdx.x;

    for (int i = tid; i < NQ; i += 256) {
        float4 q = bb[b * NQ + i];
        float cx = q.x, cy = q.y, w = q.z, h = q.w;
        float hw = 0.5f * w, hh = 0.5f * h;       // exact (pow2 scale)
        float x1 = cx - hw, y1 = cy - hh, x2 = cx + hw, y2 = cy + hh;
        sx1[i] = x1; sy1[i] = y1; sx2[i] = x2; sy2[i] = y2;
        sar[i] = (x2 - x1) * (y2 - y1);           // ref: area from xyxy
    }
    __syncthreads();

    const int wave = tid >> 6, lane = tid & 63;
    for (int r = row0; r < row0 + ROWS_PER_BLK; ++r) {
        float x1i = sx1[r], y1i = sy1[r], x2i = sx2[r], y2i = sy2[r], ai = sar[r];
        unsigned long long* rowp = bits + (size_t)(b * NQ + r) * WORDS;
        for (int t = 0; t < 4; ++t) {
            int word  = wave + 4 * t;      // 0..15
            int jbase = word << 6;
            if (jbase + 64 <= r) {         // whole word strictly below diagonal
                if (lane == 0) rowp[word] = 0ULL;
                continue;
            }
            int j = jbase + lane;
            bool pred = false;
            if (j >= r && j < NQ) {
                float x1j = sx1[j], y1j = sy1[j], x2j = sx2[j], y2j = sy2[j], aj = sar[j];
                float ltx = fmaxf(x1i, x1j), lty = fmaxf(y1i, y1j);
                float rbx = fminf(x2i, x2j), rby = fminf(y2i, y2j);
                float iw  = fmaxf(rbx - ltx, 0.0f), ih = fmaxf(rby - lty, 0.0f);
                float inter = iw * ih;
                float uni   = ai + aj - inter;
                float iou   = inter / uni;                 // 0/0 -> NaN (degenerate)
                float ex1 = fminf(x1i, x1j), ey1 = fminf(y1i, y1j);
                float ex2 = fmaxf(x2i, x2j), ey2 = fmaxf(y2i, y2j);
                float ew  = fmaxf(ex2 - ex1, 0.0f), eh2 = fmaxf(ey2 - ey1, 0.0f);
                float ae  = ew * eh2;
                float g   = iou - (ae - uni) / ae;
                pred = (g > 0.9f);                         // NaN -> false, matches np
            }
            unsigned long long m = __ballot(pred);
            if (lane == 0) rowp[word] = m;
        }
    }
}

// ---------------------------------------------------------------------------
// Kernel 2: connected components (min-label propagation, one block/batch),
// then component-mean aggregation -> f32 agg. The whole 115.2 KB bit matrix
// for the batch is staged to LDS with coalesced 16B loads ONCE, so the
// convergence loop never touches global memory (it was scattered 8B
// latency-bound loads re-issued every iteration).
// ---------------------------------------------------------------------------
__global__ __launch_bounds__(1024) void k_label(const unsigned long long* __restrict__ bits,
                                                const float4* __restrict__ bb,
                                                int* __restrict__ labg,
                                                float4* __restrict__ agg_out)
{
    __shared__ unsigned long long sbits[NQ * WORDS];   // 115200 B
    __shared__ int   lab[NQ];
    __shared__ float scx[NQ], scy[NQ], sw[NQ], sh[NQ], scnt[NQ];
    __shared__ int   changed;
    const int b   = blockIdx.x;
    const int tid = threadIdx.x;
    const size_t base = (size_t)b * NQ;

    // stage bits -> LDS (16B coalesced), zero the accumulators
    {
        const ulonglong2* src = (const ulonglong2*)(bits + base * WORDS);
        ulonglong2* dst = (ulonglong2*)sbits;
        for (int t = tid; t < NQ * WORDS / 2; t += 1024) dst[t] = src[t];
    }
    for (int i = tid; i < NQ; i += 1024) {
        scx[i] = 0.f; scy[i] = 0.f; sw[i] = 0.f; sh[i] = 0.f; scnt[i] = 0.f;
    }
    if (tid == 0) changed = 0;
    __syncthreads();

    for (int i = tid; i < NQ; i += 1024) {
        unsigned long long selfw = sbits[i * WORDS + (i >> 6)];
        bool alive = (selfw >> (i & 63)) & 1ULL;   // degenerate box: self-GIoU NaN
        lab[i] = alive ? i : -1;
    }
    __syncthreads();

    for (int iter = 0; iter < 1024; ++iter) {
        for (int i = tid; i < NQ; i += 1024) {
            int li = lab[i];
            if (li < 0) continue;
            const unsigned long long* rowp = sbits + i * WORDS;
            for (int k = i >> 6; k < 15; ++k) {
                unsigned long long w = rowp[k];
                while (w) {
                    int j = (k << 6) + __builtin_ctzll(w);
                    w &= w - 1;
                    int lj = lab[j];
                    if (lj < li)      { li = lj; changed = 1; }
                    else if (lj > li) { atomicMin(&lab[j], li); changed = 1; }
                }
            }
            if (li < lab[i]) atomicMin(&lab[i], li);
        }
        __syncthreads();
        for (int i = tid; i < NQ; i += 1024) {       // pointer-jump compress
            int li = lab[i];
            if (li > 0) {
                int l2 = lab[li];
                if (l2 < li) lab[i] = l2;            // benign race, monotone decrease
            }
        }
        __syncthreads();
        int done = (changed == 0);
        __syncthreads();
        if (done) break;
        if (tid == 0) changed = 0;
        __syncthreads();
    }

    for (int i = tid; i < NQ; i += 1024) {
        int li = lab[i];
        if (li >= 0) {
            float4 q = bb[base + i];
            atomicAdd(&scx[li], q.x);
            atomicAdd(&scy[li], q.y);
            atomicAdd(&sw [li], q.z);
            atomicAdd(&sh [li], q.w);
            atomicAdd(&scnt[li], 1.0f);
        }
    }
    __syncthreads();

    for (int i = tid; i < NQ; i += 1024) {
        int li = lab[i];
        labg[base + i] = li;
        float4 o;
        if (li >= 0) {
            float d = scnt[li] + 1e-6f;
            o.x = scx[li] / d; o.y = scy[li] / d;
            o.z = sw [li] / d; o.w = sh [li] / d;
        } else {
            o.x = 0.f; o.y = 0.f; o.z = 0.f; o.w = 0.f;   // ref: 0 / 1e-6 = 0
        }
        agg_out[base + i] = o;
    }
}

// ---------------------------------------------------------------------------
// Kernel 3: adj[b][i][j] = (lab[j]==lab[i] && alive) ? 1.0f : 0.0f
// One block per row; 16B/lane coalesced stores. Pure streaming write (104 MB).
// ---------------------------------------------------------------------------
__global__ __launch_bounds__(256) void k_adj(const int* __restrict__ labg,
                                             float4* __restrict__ adj)
{
    const int row = blockIdx.x;            // b*900 + i
    const int b = row / NQ;
    const int li = labg[row];
    const int4* lj4 = (const int4*)(labg + (size_t)b * NQ);
    float4* out = adj + (size_t)row * (NQ / 4);
    for (int t = threadIdx.x; t < NQ / 4; t += 256) {
        int4 l = lj4[t];
        float4 o;
        o.x = (l.x == li && li >= 0) ? 1.0f : 0.f;
        o.y = (l.y == li && li >= 0) ? 1.0f : 0.f;
        o.z = (l.z == li && li >= 0) ? 1.0f : 0.f;
        o.w = (l.w == li && li >= 0) ? 1.0f : 0.f;
        out[t] = o;
    }
}

// Fallback copy kernel (only used when d_ws is too small and we must alias
// scratch into the output buffer, forcing copy-last ordering).
__global__ __launch_bounds__(256) void k_copy(const float4* __restrict__ src,
                                              float4* __restrict__ dst)
{
    int i = blockIdx.x * 256 + threadIdx.x;
    if (i < LOG_F4) dst[i] = src[i];
}

extern "C" void kernel_launch(void* const* d_in, const int* in_sizes, int n_in,
                              void* d_out, int out_size, void* d_ws, size_t ws_size,
                              hipStream_t stream) {
    (void)in_sizes; (void)n_in; (void)out_size;
    const float4* bb = (const float4*)d_in[0];
    const float4* logits = (const float4*)d_in[1];
    float* outf = (float*)d_out;

    float4* agg     = (float4*)(outf + AGG_ELE);
    float4* adj     = (float4*)(outf + ADJ_ELE);
    float4* log_out = (float4*)(outf + LOG_ELE);

    if (d_ws != nullptr && ws_size >= WS_NEEDED) {
        // preferred path: scratch in workspace, 3 dispatches, copy folded
        // into the first launch (no ordering hazard with labels).
        unsigned long long* bits = (unsigned long long*)d_ws;
        int* labg = (int*)((char*)d_ws + WS_BITS_BYTES);
        hipLaunchKernelGGL(k_mask,  dim3(MASK_BLKS + COPY_BLKS), dim3(256), 0, stream,
                           bb, bits, logits, log_out);
        hipLaunchKernelGGL(k_label, dim3(NB), dim3(1024), 0, stream, bits, bb, labg, agg);
        hipLaunchKernelGGL(k_adj,   dim3(NB * NQ), dim3(256), 0, stream, labg, adj);
    } else {
        // fallback: scratch aliases output regions (bits -> adj start,
        // labels -> logits start), copy must come last.
        unsigned long long* bits = (unsigned long long*)(outf + ADJ_ELE);
        int* labg = (int*)(outf + LOG_ELE);
        hipLaunchKernelGGL(k_mask,  dim3(MASK_BLKS), dim3(256), 0, stream,
                           bb, bits, logits, log_out);
        hipLaunchKernelGGL(k_label, dim3(NB), dim3(1024), 0, stream, bits, bb, labg, agg);
        hipLaunchKernelGGL(k_adj,   dim3(NB * NQ), dim3(256), 0, stream, labg, adj);
        hipLaunchKernelGGL(k_copy,  dim3(COPY_BLKS), dim3(256), 0, stream, logits, log_out);
    }
}